// Round 8
// baseline (343.192 us; speedup 1.0000x reference)
//
#include <hip/hip_runtime.h>
#include <hip/hip_bf16.h>
#include <math.h>

#define SEQ 2048
#define HIDDEN 2048
#define NHEAD 32
#define NKVH 8
#define HD 64

typedef __bf16 bf16_t;
typedef __bf16 bf16x8 __attribute__((ext_vector_type(8)));
typedef __bf16 bf16x4 __attribute__((ext_vector_type(4)));
typedef float f32x4 __attribute__((ext_vector_type(4)));

__device__ __forceinline__ void gld_lds16(const bf16_t* g, bf16_t* l) {
  __builtin_amdgcn_global_load_lds((const __attribute__((address_space(1))) void*)g,
                                   (__attribute__((address_space(3))) void*)l, 16, 0, 0);
}

// ---------- sentinel fill (contract-violation signal), f32 ----------
__global__ __launch_bounds__(256) void k_fill(float* __restrict__ out, int n, float v) {
  int i = blockIdx.x * 256 + threadIdx.x;
  if (i < n) out[i] = v;
}

// ---------------- f32 -> bf16 convert, 4 elems/thread ----------------
__global__ __launch_bounds__(256) void k_cvt(const float* __restrict__ in,
                                             bf16_t* __restrict__ out, int n4) {
  int i = blockIdx.x * 256 + threadIdx.x;
  if (i >= n4) return;
  float4 v = ((const float4*)in)[i];
  bf16x4 o;
  o[0] = (bf16_t)v.x; o[1] = (bf16_t)v.y; o[2] = (bf16_t)v.z; o[3] = (bf16_t)v.w;
  ((bf16x4*)out)[i] = o;
}

// ------- transpose + convert: in (R x C) f32 row-major -> out (C x R) bf16 -------
__global__ __launch_bounds__(256) void k_tconv(const float* __restrict__ in,
                                               bf16_t* __restrict__ out, int R, int C) {
  __shared__ float t[64][65];
  const int c0 = blockIdx.x * 64, r0 = blockIdx.y * 64;
#pragma unroll
  for (int i = 0; i < 16; ++i) {
    int idx = threadIdx.x + i * 256;
    int r = idx >> 6, c = idx & 63;
    t[r][c] = in[(size_t)(r0 + r) * C + c0 + c];
  }
  __syncthreads();
#pragma unroll
  for (int i = 0; i < 16; ++i) {
    int idx = threadIdx.x + i * 256;
    int nr = idx >> 6, kc = idx & 63;
    out[(size_t)(c0 + nr) * R + r0 + kc] = (bf16_t)t[kc][nr];
  }
}

// ---------------- bf16 GEMM: C[M,N] = A[M,K] * Bt[N,K]^T ----------------
// r7-proven: 128x128 tile, BK=64, gld_lds w16, 3-bit XOR swizzle (conflict-free per
// r5 counters). New: 1-D grid + XCD-chunked swizzle (T1) -- consecutive wg within an
// XCD chunk share the A row-panel (same by) -> panel stays in that XCD's private L2.
template <typename OutT>
__global__ __launch_bounds__(256) void k_gemm(const bf16_t* __restrict__ A,
                                              const bf16_t* __restrict__ Bt,
                                              OutT* __restrict__ C,
                                              int M, int N, int K) {
  __shared__ __align__(16) bf16_t As[128 * 64];
  __shared__ __align__(16) bf16_t Bs[128 * 64];
  const int tid  = threadIdx.x;
  const int wave = tid >> 6, lane = tid & 63;
  const int lr = lane & 15, quad = lane >> 4;
  const int NBX = N >> 7;
  const int L = blockIdx.x, chunk = gridDim.x >> 3;      // gridDim.x % 8 == 0
  const int wg = (L & 7) * chunk + (L >> 3);             // XCD-chunked
  const int mtile = (wg / NBX) * 128, ntile = (wg % NBX) * 128;
  const int wm = (wave & 1) * 64, wn = (wave >> 1) * 64;

  const int srow = tid >> 3, sslot = tid & 7;
  const int scol = (sslot ^ (srow & 7)) * 8;
  const bf16_t* aG = A  + (size_t)(mtile + srow) * K + scol;
  const bf16_t* bG = Bt + (size_t)(ntile + srow) * K + scol;
  const size_t rstep32 = (size_t)32 * K;
  bf16_t* lA = As + tid * 8;
  bf16_t* lB = Bs + tid * 8;

  f32x4 acc[4][4];
  const f32x4 z4 = {0.f, 0.f, 0.f, 0.f};
#pragma unroll
  for (int mf = 0; mf < 4; ++mf)
#pragma unroll
    for (int nf = 0; nf < 4; ++nf) acc[mf][nf] = z4;

  for (int kt = 0; kt < K; kt += 64) {
    __syncthreads();
#pragma unroll
    for (int j = 0; j < 4; ++j) gld_lds16(aG + j * rstep32 + kt, lA + j * 2048);
#pragma unroll
    for (int j = 0; j < 4; ++j) gld_lds16(bG + j * rstep32 + kt, lB + j * 2048);
    __syncthreads();
    bf16x8 af[4][2], bfr[4][2];
#pragma unroll
    for (int mf = 0; mf < 4; ++mf)
#pragma unroll
      for (int kk = 0; kk < 2; ++kk)
        af[mf][kk] = *(const bf16x8*)(As + (wm + mf * 16 + lr) * 64 +
                                      (((kk * 4 + quad) ^ (lr & 7)) << 3));
#pragma unroll
    for (int nf = 0; nf < 4; ++nf)
#pragma unroll
      for (int kk = 0; kk < 2; ++kk)
        bfr[nf][kk] = *(const bf16x8*)(Bs + (wn + nf * 16 + lr) * 64 +
                                       (((kk * 4 + quad) ^ (lr & 7)) << 3));
#pragma unroll
    for (int mf = 0; mf < 4; ++mf)
#pragma unroll
      for (int nf = 0; nf < 4; ++nf)
#pragma unroll
        for (int kk = 0; kk < 2; ++kk)
          acc[mf][nf] = __builtin_amdgcn_mfma_f32_16x16x32_bf16(af[mf][kk], bfr[nf][kk],
                                                                acc[mf][nf], 0, 0, 0);
  }
#pragma unroll
  for (int mf = 0; mf < 4; ++mf)
#pragma unroll
    for (int nf = 0; nf < 4; ++nf)
#pragma unroll
      for (int r = 0; r < 4; ++r)
        C[(size_t)(mtile + wm + mf * 16 + quad * 4 + r) * N + ntile + wn + nf * 16 + lr] =
            (OutT)acc[mf][nf][r];
}

// ------- qkv GEMM with fused RoPE epilogue: writes ql (scaled), kl, vbuf directly -------
// ql scale = 0.125 * log2(e): scores arrive in log2-domain so attn uses exp2 directly
// (exp2(log2e*x) == exp(x), exact). XCD-chunked 1-D grid as k_gemm.
__global__ __launch_bounds__(256) void k_gemm_qkv(const bf16_t* __restrict__ A,
                                                  const bf16_t* __restrict__ Bt,
                                                  const unsigned* __restrict__ pos,
                                                  bf16_t* __restrict__ ql,
                                                  bf16_t* __restrict__ kl,
                                                  bf16_t* __restrict__ vbuf,
                                                  int K) {
  __shared__ __align__(16) bf16_t As[128 * 64];
  __shared__ __align__(16) bf16_t Bs[128 * 64];
  const int tid  = threadIdx.x;
  const int wave = tid >> 6, lane = tid & 63;
  const int lr = lane & 15, quad = lane >> 4;
  const int NBX = 24;                                    // 3072 / 128
  const int L = blockIdx.x, chunk = gridDim.x >> 3;
  const int wg = (L & 7) * chunk + (L >> 3);             // XCD-chunked
  const int mtile = (wg / NBX) * 128, ntile = (wg % NBX) * 128;
  const int wm = (wave & 1) * 64, wn = (wave >> 1) * 64;

  const int srow = tid >> 3, sslot = tid & 7;
  const int scol = (sslot ^ (srow & 7)) * 8;
  const bf16_t* aG = A  + (size_t)(mtile + srow) * K + scol;
  const bf16_t* bG = Bt + (size_t)(ntile + srow) * K + scol;
  const size_t rstep32 = (size_t)32 * K;
  bf16_t* lA = As + tid * 8;
  bf16_t* lB = Bs + tid * 8;

  f32x4 acc[4][4];
  const f32x4 z4 = {0.f, 0.f, 0.f, 0.f};
#pragma unroll
  for (int mf = 0; mf < 4; ++mf)
#pragma unroll
    for (int nf = 0; nf < 4; ++nf) acc[mf][nf] = z4;

  for (int kt = 0; kt < K; kt += 64) {
    __syncthreads();
#pragma unroll
    for (int j = 0; j < 4; ++j) gld_lds16(aG + j * rstep32 + kt, lA + j * 2048);
#pragma unroll
    for (int j = 0; j < 4; ++j) gld_lds16(bG + j * rstep32 + kt, lB + j * 2048);
    __syncthreads();
    bf16x8 af[4][2], bfr[4][2];
#pragma unroll
    for (int mf = 0; mf < 4; ++mf)
#pragma unroll
      for (int kk = 0; kk < 2; ++kk)
        af[mf][kk] = *(const bf16x8*)(As + (wm + mf * 16 + lr) * 64 +
                                      (((kk * 4 + quad) ^ (lr & 7)) << 3));
#pragma unroll
    for (int nf = 0; nf < 4; ++nf)
#pragma unroll
      for (int kk = 0; kk < 2; ++kk)
        bfr[nf][kk] = *(const bf16x8*)(Bs + (wn + nf * 16 + lr) * 64 +
                                       (((kk * 4 + quad) ^ (lr & 7)) << 3));
#pragma unroll
    for (int mf = 0; mf < 4; ++mf)
#pragma unroll
      for (int nf = 0; nf < 4; ++nf)
#pragma unroll
        for (int kk = 0; kk < 2; ++kk)
          acc[mf][nf] = __builtin_amdgcn_mfma_f32_16x16x32_bf16(af[mf][kk], bfr[nf][kk],
                                                                acc[mf][nf], 0, 0, 0);
  }

  const int colbase = ntile + wn;                // 64-aligned, wave-uniform
  if (colbase < 2560) {                          // q or k head: apply RoPE
    const bool isq = colbase < 2048;
    const int h = isq ? (colbase >> 6) : ((colbase - 2048) >> 6);
    bf16_t* obase = isq ? ql : kl;
    const int nhh = isq ? NHEAD : NKVH;
    const float scale = isq ? 0.18033688011112042f : 1.0f;   // 0.125 * log2(e)
    const float invf0 = exp2f((float)lr * -0.41524101186092029f);
    const float invf1 = exp2f((float)(lr + 16) * -0.41524101186092029f);
#pragma unroll
    for (int mf = 0; mf < 4; ++mf)
#pragma unroll
      for (int r = 0; r < 4; ++r) {
        int row = mtile + wm + mf * 16 + quad * 4 + r;
        int b = row >> 11, s = row & 2047;
        unsigned u = pos[row];
        float p = (u >= 0x3F800000u) ? __uint_as_float(u) : (float)(int)u;
#pragma unroll
        for (int nf = 0; nf < 2; ++nf) {
          float x1 = acc[mf][nf][r], x2 = acc[mf][nf + 2][r];
          float sn, cs;
          sincosf(p * (nf ? invf1 : invf0), &sn, &cs);
          size_t base = (((size_t)b * nhh + h) * SEQ + s) * HD + nf * 16 + lr;
          obase[base]      = (bf16_t)((x1 * cs - x2 * sn) * scale);
          obase[base + 32] = (bf16_t)((x2 * cs + x1 * sn) * scale);
        }
      }
  } else {                                       // v head: plain convert to compact vbuf
    const int kvh = (colbase - 2560) >> 6;
#pragma unroll
    for (int mf = 0; mf < 4; ++mf)
#pragma unroll
      for (int nf = 0; nf < 4; ++nf)
#pragma unroll
        for (int r = 0; r < 4; ++r) {
          int row = mtile + wm + mf * 16 + quad * 4 + r;
          vbuf[(size_t)row * 512 + kvh * 64 + nf * 16 + lr] = (bf16_t)acc[mf][nf][r];
        }
  }
}

// ---------------- V transpose: vbuf (b,s,kvh,d) -> vt (b,kvh,hd,s) ----------------
__global__ __launch_bounds__(256) void k_vtrans(const bf16_t* __restrict__ vbuf,
                                                bf16_t* __restrict__ vt) {
  __shared__ bf16_t t[64][66];
  const int s0 = blockIdx.x * 64;
  const int bk = blockIdx.y;
  const int b = bk >> 3, kvh = bk & 7;
#pragma unroll
  for (int i = 0; i < 16; ++i) {
    int idx = threadIdx.x + i * 256;
    int r = idx >> 6, c = idx & 63;
    t[r][c] = vbuf[((size_t)b * SEQ + s0 + r) * 512 + kvh * 64 + c];
  }
  __syncthreads();
#pragma unroll
  for (int i = 0; i < 16; ++i) {
    int idx = threadIdx.x + i * 256;
    int dr = idx >> 6, sc = idx & 63;
    vt[(((size_t)b * NKVH + kvh) * HD + dr) * SEQ + s0 + sc] = t[sc][dr];
  }
}

// ------- Flash attention v6: log2-domain softmax (scores pre-scaled by log2e) -------
// exp2f replaces __expf (saves the v_mul x log2e per exp on the VALU-bound path);
// identical math: exp2(log2e*(s-m)) == exp(s-m). Deferred denominator + THR=8
// defer-rescale (THR now in log2 units -> P bounded by 2^8, f32 accum safe).
__global__ __launch_bounds__(256, 4) void k_attn(const bf16_t* __restrict__ ql,
                                                 const bf16_t* __restrict__ kl,
                                                 const bf16_t* __restrict__ vt,
                                                 bf16_t* __restrict__ attn) {
  __shared__ __align__(16) bf16_t Ks[2][64 * 64];
  __shared__ __align__(16) bf16_t Vs[2][64 * 64];
  __shared__ __align__(16) bf16_t P[4][16 * 64];
  const int pairp = blockIdx.x;                  // 0..15
  const int bh = blockIdx.y;
  const int b = bh >> 5, h = bh & 31;
  const int kvh = h >> 2;                        // GROUP=4
  const int wave = threadIdx.x >> 6, lane = threadIdx.x & 63;
  const int lr = lane & 15, quad = lane >> 4;
  const int lhi = lane >> 3, llo = lane & 7;
  const int gsw = llo ^ lhi;
  const bf16_t* qp = ql + ((size_t)b * NHEAD + h) * SEQ * HD;
  const bf16_t* kp = kl + ((size_t)b * NKVH + kvh) * SEQ * HD;
  const bf16_t* vp = vt + ((size_t)b * NKVH + kvh) * HD * SEQ;
  const f32x4 z4 = {0.f, 0.f, 0.f, 0.f};

  auto stage = [&](int buf, int kt) {
    const int k0s = kt * 64;
    const bf16_t* kbase = kp + (size_t)k0s * HD;
#pragma unroll
    for (int j = 0; j < 2; ++j) {
      int key = (wave * 2 + j) * 8 + lhi;
      gld_lds16(kbase + (size_t)key * HD + gsw * 8, &Ks[buf][(wave * 2 + j) * 512 + lane * 8]);
    }
#pragma unroll
    for (int j = 0; j < 2; ++j) {
      int hd = wave * 16 + j * 8 + lhi;
      gld_lds16(vp + (size_t)hd * SEQ + k0s + gsw * 8, &Vs[buf][(wave * 16 + j * 8) * 64 + lane * 8]);
    }
  };

#pragma unroll
  for (int seg = 0; seg < 2; ++seg) {
    const int tile = seg ? pairp : 31 - pairp;   // long tile first
    const int q0 = tile * 64 + wave * 16;

    bf16x8 aq[2];
#pragma unroll
    for (int ks = 0; ks < 2; ++ks)
      aq[ks] = *(const bf16x8*)(qp + (size_t)(q0 + lr) * HD + ks * 32 + quad * 8);

    f32x4 acc[4];
    float mrow[4], lrow[4];
#pragma unroll
    for (int nf = 0; nf < 4; ++nf) acc[nf] = z4;
#pragma unroll
    for (int r = 0; r < 4; ++r) { mrow[r] = -1e30f; lrow[r] = 0.f; }

    const int ntiles = tile + 1;                 // uniform across the block
    int cur = 0;
    stage(0, 0);
    __syncthreads();                             // prologue loads resident

    for (int kt = 0; kt < ntiles; ++kt) {
      const int k0 = kt * 64;
      if (kt + 1 < ntiles) stage(cur ^ 1, kt + 1);  // prefetch hides under compute

      bf16x8 bk[2][4];
#pragma unroll
      for (int ks = 0; ks < 2; ++ks)
#pragma unroll
        for (int nh = 0; nh < 4; ++nh)
          bk[ks][nh] = *(const bf16x8*)(&Ks[cur][(nh * 16 + lr) * 64 + (((ks * 4 + quad) ^ (lr & 7)) << 3)]);
      f32x4 sc[4];
#pragma unroll
      for (int nh = 0; nh < 4; ++nh) {
        sc[nh] = __builtin_amdgcn_mfma_f32_16x16x32_bf16(aq[0], bk[0][nh], z4, 0, 0, 0);
        sc[nh] = __builtin_amdgcn_mfma_f32_16x16x32_bf16(aq[1], bk[1][nh], sc[nh], 0, 0, 0);
      }

      if (kt == ntiles - 1) {                    // diagonal tile: causal mask (all waves)
#pragma unroll
        for (int nh = 0; nh < 4; ++nh)
#pragma unroll
          for (int r = 0; r < 4; ++r) {
            int qg = q0 + quad * 4 + r;
            int kg = k0 + nh * 16 + lr;
            if (kg > qg) sc[nh][r] = -1e30f;
          }
      }

      // online softmax (log2 domain): single max tree; deferred denominator; THR=8
      float rm[4];
#pragma unroll
      for (int r = 0; r < 4; ++r)
        rm[r] = fmaxf(fmaxf(sc[0][r], sc[1][r]), fmaxf(sc[2][r], sc[3][r]));
#pragma unroll
      for (int off = 1; off < 16; off <<= 1)
#pragma unroll
        for (int r = 0; r < 4; ++r) rm[r] = fmaxf(rm[r], __shfl_xor(rm[r], off, 64));
      int ng = (rm[0] <= mrow[0] + 8.f) & (rm[1] <= mrow[1] + 8.f) &
               (rm[2] <= mrow[2] + 8.f) & (rm[3] <= mrow[3] + 8.f);
      if (!__all(ng)) {
#pragma unroll
        for (int r = 0; r < 4; ++r) {
          float mn = fmaxf(mrow[r], rm[r]);
          float al = exp2f(mrow[r] - mn);
          mrow[r] = mn;
          lrow[r] *= al;
#pragma unroll
          for (int nf = 0; nf < 4; ++nf) acc[nf][r] *= al;
        }
      }
#pragma unroll
      for (int nh = 0; nh < 4; ++nh)
#pragma unroll
        for (int r = 0; r < 4; ++r) sc[nh][r] = exp2f(sc[nh][r] - mrow[r]);
#pragma unroll
      for (int r = 0; r < 4; ++r)
        lrow[r] += (sc[0][r] + sc[1][r]) + (sc[2][r] + sc[3][r]);   // per-lane partial
#pragma unroll
      for (int nh = 0; nh < 4; ++nh)
#pragma unroll
        for (int r = 0; r < 4; ++r) {
          int row = quad * 4 + r;
          int cg = (nh * 2 + (lr >> 3)) ^ (row & 7);
          P[wave][row * 64 + (cg << 3) + (lr & 7)] = (bf16_t)sc[nh][r];
        }
      // per-wave C->A handoff; DS pipe in-order per wave
      __asm__ volatile("s_waitcnt lgkmcnt(0)" ::: "memory");
      bf16x8 pa[2], bv[2][4];
#pragma unroll
      for (int kg = 0; kg < 2; ++kg)
        pa[kg] = *(const bf16x8*)(&P[wave][lr * 64 + (((kg * 4 + quad) ^ (lr & 7)) << 3)]);
#pragma unroll
      for (int kg = 0; kg < 2; ++kg)
#pragma unroll
        for (int nf = 0; nf < 4; ++nf)
          bv[kg][nf] = *(const bf16x8*)(&Vs[cur][(nf * 16 + lr) * 64 + (((kg * 4 + quad) ^ (lr & 7)) << 3)]);
      __asm__ volatile("" ::: "memory");
#pragma unroll
      for (int nf = 0; nf < 4; ++nf) {
        acc[nf] = __builtin_amdgcn_mfma_f32_16x16x32_bf16(pa[0], bv[0][nf], acc[nf], 0, 0, 0);
        acc[nf] = __builtin_amdgcn_mfma_f32_16x16x32_bf16(pa[1], bv[1][nf], acc[nf], 0, 0, 0);
      }
      __syncthreads();                           // prefetched loads drained; buf handoff
      cur ^= 1;
    }

    // one denominator tree per segment (was per-tile)
#pragma unroll
    for (int off = 1; off < 16; off <<= 1)
#pragma unroll
      for (int r = 0; r < 4; ++r) lrow[r] += __shfl_xor(lrow[r], off, 64);

#pragma unroll
    for (int r = 0; r < 4; ++r) {
      float inv = 1.f / lrow[r];
      int row = q0 + quad * 4 + r;
#pragma unroll
      for (int nf = 0; nf < 4; ++nf)
        attn[((size_t)b * SEQ + row) * HIDDEN + h * HD + nf * 16 + lr] =
            (bf16_t)(acc[nf][r] * inv);
    }
  }
}

extern "C" void kernel_launch(void* const* d_in, const int* in_sizes, int n_in,
                              void* d_out, int out_size, void* d_ws, size_t ws_size,
                              hipStream_t stream) {
  float* out = (float*)d_out;

  if (n_in != 4) { k_fill<<<dim3(32768), dim3(256), 0, stream>>>(out, 8388608, 222.0f); return; }
  if (out_size != 8388608) { k_fill<<<dim3(32768), dim3(256), 0, stream>>>(out, 8388608, 111.0f); return; }
  if (ws_size < (size_t)109051904) { k_fill<<<dim3(32768), dim3(256), 0, stream>>>(out, 8388608, 777.0f); return; }

  int ord[4] = {0, 1, 2, 3};
  for (int i = 1; i < 4; ++i)
    for (int j = i; j > 0 && in_sizes[ord[j]] > in_sizes[ord[j - 1]]; --j) {
      int t = ord[j]; ord[j] = ord[j - 1]; ord[j - 1] = t;
    }
  const float*    hidden    = (const float*)d_in[ord[0]];
  const float*    wqkv      = (const float*)d_in[ord[1]];
  const float*    wo        = (const float*)d_in[ord[2]];
  const unsigned* positions = (const unsigned*)d_in[ord[3]];

  char* ws = (char*)d_ws;
  bf16_t* hidB  = (bf16_t*)(ws + 0);
  bf16_t* wqkvT = (bf16_t*)(ws + 16777216);
  bf16_t* woT   = (bf16_t*)(ws + 29360128);
  bf16_t* vbuf  = (bf16_t*)(ws + 37748736);   // 4096 x 512 bf16 = 4 MB
  bf16_t* ql    = (bf16_t*)(ws + 62914560);
  bf16_t* kl    = (bf16_t*)(ws + 79691776);
  bf16_t* vt    = (bf16_t*)(ws + 83886080);
  bf16_t* attnb = (bf16_t*)(ws + 88080384);

  k_cvt<<<dim3(8192), dim3(256), 0, stream>>>(hidden, hidB, 2097152);
  k_tconv<<<dim3(48, 32), dim3(256), 0, stream>>>(wqkv, wqkvT, 2048, 3072);
  k_tconv<<<dim3(32, 32), dim3(256), 0, stream>>>(wo, woT, 2048, 2048);
  k_gemm_qkv<<<dim3(768), dim3(256), 0, stream>>>(hidB, wqkvT, positions, ql, kl, vbuf, 2048);
  k_vtrans<<<dim3(32, 16), dim3(256), 0, stream>>>(vbuf, vt);
  k_attn<<<dim3(16, 64), dim3(256), 0, stream>>>(ql, kl, vt, attnb);
  k_gemm<float><<<dim3(512), dim3(256), 0, stream>>>(attnb, woT, out, 4096, 2048, 2048);
}

// Round 9
// 317.856 us; speedup vs baseline: 1.0797x; 1.0797x over previous
//
#include <hip/hip_runtime.h>
#include <hip/hip_bf16.h>
#include <math.h>

#define SEQ 2048
#define HIDDEN 2048
#define NHEAD 32
#define NKVH 8
#define HD 64

typedef __bf16 bf16_t;
typedef __bf16 bf16x8 __attribute__((ext_vector_type(8)));
typedef __bf16 bf16x4 __attribute__((ext_vector_type(4)));
typedef float f32x4 __attribute__((ext_vector_type(4)));

__device__ __forceinline__ void gld_lds16(const bf16_t* g, bf16_t* l) {
  __builtin_amdgcn_global_load_lds((const __attribute__((address_space(1))) void*)g,
                                   (__attribute__((address_space(3))) void*)l, 16, 0, 0);
}

// raw v_exp_f32: D = 2^S0 (one trans op; denormal flush fine for softmax)
__device__ __forceinline__ float exp2_raw(float x) {
  return __builtin_amdgcn_exp2f(x);
}

// ---------- sentinel fill (contract-violation signal), f32 ----------
__global__ __launch_bounds__(256) void k_fill(float* __restrict__ out, int n, float v) {
  int i = blockIdx.x * 256 + threadIdx.x;
  if (i < n) out[i] = v;
}

// ---------------- f32 -> bf16 convert, 4 elems/thread ----------------
__global__ __launch_bounds__(256) void k_cvt(const float* __restrict__ in,
                                             bf16_t* __restrict__ out, int n4) {
  int i = blockIdx.x * 256 + threadIdx.x;
  if (i >= n4) return;
  float4 v = ((const float4*)in)[i];
  bf16x4 o;
  o[0] = (bf16_t)v.x; o[1] = (bf16_t)v.y; o[2] = (bf16_t)v.z; o[3] = (bf16_t)v.w;
  ((bf16x4*)out)[i] = o;
}

// ------- transpose + convert: in (R x C) f32 row-major -> out (C x R) bf16 -------
__global__ __launch_bounds__(256) void k_tconv(const float* __restrict__ in,
                                               bf16_t* __restrict__ out, int R, int C) {
  __shared__ float t[64][65];
  const int c0 = blockIdx.x * 64, r0 = blockIdx.y * 64;
#pragma unroll
  for (int i = 0; i < 16; ++i) {
    int idx = threadIdx.x + i * 256;
    int r = idx >> 6, c = idx & 63;
    t[r][c] = in[(size_t)(r0 + r) * C + c0 + c];
  }
  __syncthreads();
#pragma unroll
  for (int i = 0; i < 16; ++i) {
    int idx = threadIdx.x + i * 256;
    int nr = idx >> 6, kc = idx & 63;
    out[(size_t)(c0 + nr) * R + r0 + kc] = (bf16_t)t[kc][nr];
  }
}

// ---------------- bf16 GEMM: C[M,N] = A[M,K] * Bt[N,K]^T ----------------
// r7-proven: 128x128 tile, BK=64, gld_lds w16, 3-bit XOR swizzle (conflict-free
// per r5 counters), 2-D grid (r8's XCD chunking reverted: non-attn 221->229).
template <typename OutT>
__global__ __launch_bounds__(256) void k_gemm(const bf16_t* __restrict__ A,
                                              const bf16_t* __restrict__ Bt,
                                              OutT* __restrict__ C,
                                              int M, int N, int K) {
  __shared__ __align__(16) bf16_t As[128 * 64];
  __shared__ __align__(16) bf16_t Bs[128 * 64];
  const int tid  = threadIdx.x;
  const int wave = tid >> 6, lane = tid & 63;
  const int lr = lane & 15, quad = lane >> 4;
  const int mtile = blockIdx.y * 128, ntile = blockIdx.x * 128;
  const int wm = (wave & 1) * 64, wn = (wave >> 1) * 64;

  const int srow = tid >> 3, sslot = tid & 7;
  const int scol = (sslot ^ (srow & 7)) * 8;
  const bf16_t* aG = A  + (size_t)(mtile + srow) * K + scol;
  const bf16_t* bG = Bt + (size_t)(ntile + srow) * K + scol;
  const size_t rstep32 = (size_t)32 * K;
  bf16_t* lA = As + tid * 8;
  bf16_t* lB = Bs + tid * 8;

  f32x4 acc[4][4];
  const f32x4 z4 = {0.f, 0.f, 0.f, 0.f};
#pragma unroll
  for (int mf = 0; mf < 4; ++mf)
#pragma unroll
    for (int nf = 0; nf < 4; ++nf) acc[mf][nf] = z4;

  for (int kt = 0; kt < K; kt += 64) {
    __syncthreads();
#pragma unroll
    for (int j = 0; j < 4; ++j) gld_lds16(aG + j * rstep32 + kt, lA + j * 2048);
#pragma unroll
    for (int j = 0; j < 4; ++j) gld_lds16(bG + j * rstep32 + kt, lB + j * 2048);
    __syncthreads();
    bf16x8 af[4][2], bfr[4][2];
#pragma unroll
    for (int mf = 0; mf < 4; ++mf)
#pragma unroll
      for (int kk = 0; kk < 2; ++kk)
        af[mf][kk] = *(const bf16x8*)(As + (wm + mf * 16 + lr) * 64 +
                                      (((kk * 4 + quad) ^ (lr & 7)) << 3));
#pragma unroll
    for (int nf = 0; nf < 4; ++nf)
#pragma unroll
      for (int kk = 0; kk < 2; ++kk)
        bfr[nf][kk] = *(const bf16x8*)(Bs + (wn + nf * 16 + lr) * 64 +
                                       (((kk * 4 + quad) ^ (lr & 7)) << 3));
#pragma unroll
    for (int mf = 0; mf < 4; ++mf)
#pragma unroll
      for (int nf = 0; nf < 4; ++nf)
#pragma unroll
        for (int kk = 0; kk < 2; ++kk)
          acc[mf][nf] = __builtin_amdgcn_mfma_f32_16x16x32_bf16(af[mf][kk], bfr[nf][kk],
                                                                acc[mf][nf], 0, 0, 0);
  }
#pragma unroll
  for (int mf = 0; mf < 4; ++mf)
#pragma unroll
    for (int nf = 0; nf < 4; ++nf)
#pragma unroll
      for (int r = 0; r < 4; ++r)
        C[(size_t)(mtile + wm + mf * 16 + quad * 4 + r) * N + ntile + wn + nf * 16 + lr] =
            (OutT)acc[mf][nf][r];
}

// ------- qkv GEMM with fused RoPE epilogue: writes ql (scaled), kl, vbuf directly -------
// ql scale = 0.125 * log2(e): scores arrive in log2-domain so attn's v_exp_f32
// computes exp(s-m) exactly (exp2(log2e*x) == exp(x)).
__global__ __launch_bounds__(256) void k_gemm_qkv(const bf16_t* __restrict__ A,
                                                  const bf16_t* __restrict__ Bt,
                                                  const unsigned* __restrict__ pos,
                                                  bf16_t* __restrict__ ql,
                                                  bf16_t* __restrict__ kl,
                                                  bf16_t* __restrict__ vbuf,
                                                  int K) {
  __shared__ __align__(16) bf16_t As[128 * 64];
  __shared__ __align__(16) bf16_t Bs[128 * 64];
  const int tid  = threadIdx.x;
  const int wave = tid >> 6, lane = tid & 63;
  const int lr = lane & 15, quad = lane >> 4;
  const int mtile = blockIdx.y * 128, ntile = blockIdx.x * 128;
  const int wm = (wave & 1) * 64, wn = (wave >> 1) * 64;

  const int srow = tid >> 3, sslot = tid & 7;
  const int scol = (sslot ^ (srow & 7)) * 8;
  const bf16_t* aG = A  + (size_t)(mtile + srow) * K + scol;
  const bf16_t* bG = Bt + (size_t)(ntile + srow) * K + scol;
  const size_t rstep32 = (size_t)32 * K;
  bf16_t* lA = As + tid * 8;
  bf16_t* lB = Bs + tid * 8;

  f32x4 acc[4][4];
  const f32x4 z4 = {0.f, 0.f, 0.f, 0.f};
#pragma unroll
  for (int mf = 0; mf < 4; ++mf)
#pragma unroll
    for (int nf = 0; nf < 4; ++nf) acc[mf][nf] = z4;

  for (int kt = 0; kt < K; kt += 64) {
    __syncthreads();
#pragma unroll
    for (int j = 0; j < 4; ++j) gld_lds16(aG + j * rstep32 + kt, lA + j * 2048);
#pragma unroll
    for (int j = 0; j < 4; ++j) gld_lds16(bG + j * rstep32 + kt, lB + j * 2048);
    __syncthreads();
    bf16x8 af[4][2], bfr[4][2];
#pragma unroll
    for (int mf = 0; mf < 4; ++mf)
#pragma unroll
      for (int kk = 0; kk < 2; ++kk)
        af[mf][kk] = *(const bf16x8*)(As + (wm + mf * 16 + lr) * 64 +
                                      (((kk * 4 + quad) ^ (lr & 7)) << 3));
#pragma unroll
    for (int nf = 0; nf < 4; ++nf)
#pragma unroll
      for (int kk = 0; kk < 2; ++kk)
        bfr[nf][kk] = *(const bf16x8*)(Bs + (wn + nf * 16 + lr) * 64 +
                                       (((kk * 4 + quad) ^ (lr & 7)) << 3));
#pragma unroll
    for (int mf = 0; mf < 4; ++mf)
#pragma unroll
      for (int nf = 0; nf < 4; ++nf)
#pragma unroll
        for (int kk = 0; kk < 2; ++kk)
          acc[mf][nf] = __builtin_amdgcn_mfma_f32_16x16x32_bf16(af[mf][kk], bfr[nf][kk],
                                                                acc[mf][nf], 0, 0, 0);
  }

  const int colbase = ntile + wn;                // 64-aligned, wave-uniform
  if (colbase < 2560) {                          // q or k head: apply RoPE
    const bool isq = colbase < 2048;
    const int h = isq ? (colbase >> 6) : ((colbase - 2048) >> 6);
    bf16_t* obase = isq ? ql : kl;
    const int nhh = isq ? NHEAD : NKVH;
    const float scale = isq ? 0.18033688011112042f : 1.0f;   // 0.125 * log2(e)
    const float invf0 = exp2f((float)lr * -0.41524101186092029f);
    const float invf1 = exp2f((float)(lr + 16) * -0.41524101186092029f);
#pragma unroll
    for (int mf = 0; mf < 4; ++mf)
#pragma unroll
      for (int r = 0; r < 4; ++r) {
        int row = mtile + wm + mf * 16 + quad * 4 + r;
        int b = row >> 11, s = row & 2047;
        unsigned u = pos[row];
        float p = (u >= 0x3F800000u) ? __uint_as_float(u) : (float)(int)u;
#pragma unroll
        for (int nf = 0; nf < 2; ++nf) {
          float x1 = acc[mf][nf][r], x2 = acc[mf][nf + 2][r];
          float sn, cs;
          sincosf(p * (nf ? invf1 : invf0), &sn, &cs);
          size_t base = (((size_t)b * nhh + h) * SEQ + s) * HD + nf * 16 + lr;
          obase[base]      = (bf16_t)((x1 * cs - x2 * sn) * scale);
          obase[base + 32] = (bf16_t)((x2 * cs + x1 * sn) * scale);
        }
      }
  } else {                                       // v head: plain convert to compact vbuf
    const int kvh = (colbase - 2560) >> 6;
#pragma unroll
    for (int mf = 0; mf < 4; ++mf)
#pragma unroll
      for (int nf = 0; nf < 4; ++nf)
#pragma unroll
        for (int r = 0; r < 4; ++r) {
          int row = mtile + wm + mf * 16 + quad * 4 + r;
          vbuf[(size_t)row * 512 + kvh * 64 + nf * 16 + lr] = (bf16_t)acc[mf][nf][r];
        }
  }
}

// ---------------- V transpose: vbuf (b,s,kvh,d) -> vt (b,kvh,hd,s) ----------------
__global__ __launch_bounds__(256) void k_vtrans(const bf16_t* __restrict__ vbuf,
                                                bf16_t* __restrict__ vt) {
  __shared__ bf16_t t[64][66];
  const int s0 = blockIdx.x * 64;
  const int bk = blockIdx.y;
  const int b = bk >> 3, kvh = bk & 7;
#pragma unroll
  for (int i = 0; i < 16; ++i) {
    int idx = threadIdx.x + i * 256;
    int r = idx >> 6, c = idx & 63;
    t[r][c] = vbuf[((size_t)b * SEQ + s0 + r) * 512 + kvh * 64 + c];
  }
  __syncthreads();
#pragma unroll
  for (int i = 0; i < 16; ++i) {
    int idx = threadIdx.x + i * 256;
    int dr = idx >> 6, sc = idx & 63;
    vt[(((size_t)b * NKVH + kvh) * HD + dr) * SEQ + s0 + sc] = t[sc][dr];
  }
}

// ------- Flash attention v7: log2-domain softmax with RAW v_exp_f32 -------
// Scores pre-scaled by log2e in the qkv epilogue; __builtin_amdgcn_exp2f is a
// single v_exp_f32 (no libm wrapper -- r8's exp2f regressed VALUBusy 48->56).
// Deferred denominator + THR=8 defer-rescale (log2 units -> P <= 2^8).
__global__ __launch_bounds__(256, 4) void k_attn(const bf16_t* __restrict__ ql,
                                                 const bf16_t* __restrict__ kl,
                                                 const bf16_t* __restrict__ vt,
                                                 bf16_t* __restrict__ attn) {
  __shared__ __align__(16) bf16_t Ks[2][64 * 64];
  __shared__ __align__(16) bf16_t Vs[2][64 * 64];
  __shared__ __align__(16) bf16_t P[4][16 * 64];
  const int pairp = blockIdx.x;                  // 0..15
  const int bh = blockIdx.y;
  const int b = bh >> 5, h = bh & 31;
  const int kvh = h >> 2;                        // GROUP=4
  const int wave = threadIdx.x >> 6, lane = threadIdx.x & 63;
  const int lr = lane & 15, quad = lane >> 4;
  const int lhi = lane >> 3, llo = lane & 7;
  const int gsw = llo ^ lhi;
  const bf16_t* qp = ql + ((size_t)b * NHEAD + h) * SEQ * HD;
  const bf16_t* kp = kl + ((size_t)b * NKVH + kvh) * SEQ * HD;
  const bf16_t* vp = vt + ((size_t)b * NKVH + kvh) * HD * SEQ;
  const f32x4 z4 = {0.f, 0.f, 0.f, 0.f};

  auto stage = [&](int buf, int kt) {
    const int k0s = kt * 64;
    const bf16_t* kbase = kp + (size_t)k0s * HD;
#pragma unroll
    for (int j = 0; j < 2; ++j) {
      int key = (wave * 2 + j) * 8 + lhi;
      gld_lds16(kbase + (size_t)key * HD + gsw * 8, &Ks[buf][(wave * 2 + j) * 512 + lane * 8]);
    }
#pragma unroll
    for (int j = 0; j < 2; ++j) {
      int hd = wave * 16 + j * 8 + lhi;
      gld_lds16(vp + (size_t)hd * SEQ + k0s + gsw * 8, &Vs[buf][(wave * 16 + j * 8) * 64 + lane * 8]);
    }
  };

#pragma unroll
  for (int seg = 0; seg < 2; ++seg) {
    const int tile = seg ? pairp : 31 - pairp;   // long tile first
    const int q0 = tile * 64 + wave * 16;

    bf16x8 aq[2];
#pragma unroll
    for (int ks = 0; ks < 2; ++ks)
      aq[ks] = *(const bf16x8*)(qp + (size_t)(q0 + lr) * HD + ks * 32 + quad * 8);

    f32x4 acc[4];
    float mrow[4], lrow[4];
#pragma unroll
    for (int nf = 0; nf < 4; ++nf) acc[nf] = z4;
#pragma unroll
    for (int r = 0; r < 4; ++r) { mrow[r] = -1e30f; lrow[r] = 0.f; }

    const int ntiles = tile + 1;                 // uniform across the block
    int cur = 0;
    stage(0, 0);
    __syncthreads();                             // prologue loads resident

    for (int kt = 0; kt < ntiles; ++kt) {
      const int k0 = kt * 64;
      if (kt + 1 < ntiles) stage(cur ^ 1, kt + 1);  // prefetch hides under compute

      bf16x8 bk[2][4];
#pragma unroll
      for (int ks = 0; ks < 2; ++ks)
#pragma unroll
        for (int nh = 0; nh < 4; ++nh)
          bk[ks][nh] = *(const bf16x8*)(&Ks[cur][(nh * 16 + lr) * 64 + (((ks * 4 + quad) ^ (lr & 7)) << 3)]);
      f32x4 sc[4];
#pragma unroll
      for (int nh = 0; nh < 4; ++nh) {
        sc[nh] = __builtin_amdgcn_mfma_f32_16x16x32_bf16(aq[0], bk[0][nh], z4, 0, 0, 0);
        sc[nh] = __builtin_amdgcn_mfma_f32_16x16x32_bf16(aq[1], bk[1][nh], sc[nh], 0, 0, 0);
      }

      if (kt == ntiles - 1) {                    // diagonal tile: causal mask (all waves)
#pragma unroll
        for (int nh = 0; nh < 4; ++nh)
#pragma unroll
          for (int r = 0; r < 4; ++r) {
            int qg = q0 + quad * 4 + r;
            int kg = k0 + nh * 16 + lr;
            if (kg > qg) sc[nh][r] = -1e30f;
          }
      }

      // online softmax (log2 domain, raw v_exp): single max tree; deferred denom; THR=8
      float rm[4];
#pragma unroll
      for (int r = 0; r < 4; ++r)
        rm[r] = fmaxf(fmaxf(sc[0][r], sc[1][r]), fmaxf(sc[2][r], sc[3][r]));
#pragma unroll
      for (int off = 1; off < 16; off <<= 1)
#pragma unroll
        for (int r = 0; r < 4; ++r) rm[r] = fmaxf(rm[r], __shfl_xor(rm[r], off, 64));
      int ng = (rm[0] <= mrow[0] + 8.f) & (rm[1] <= mrow[1] + 8.f) &
               (rm[2] <= mrow[2] + 8.f) & (rm[3] <= mrow[3] + 8.f);
      if (!__all(ng)) {
#pragma unroll
        for (int r = 0; r < 4; ++r) {
          float mn = fmaxf(mrow[r], rm[r]);
          float al = exp2_raw(mrow[r] - mn);
          mrow[r] = mn;
          lrow[r] *= al;
#pragma unroll
          for (int nf = 0; nf < 4; ++nf) acc[nf][r] *= al;
        }
      }
#pragma unroll
      for (int nh = 0; nh < 4; ++nh)
#pragma unroll
        for (int r = 0; r < 4; ++r) sc[nh][r] = exp2_raw(sc[nh][r] - mrow[r]);
#pragma unroll
      for (int r = 0; r < 4; ++r)
        lrow[r] += (sc[0][r] + sc[1][r]) + (sc[2][r] + sc[3][r]);   // per-lane partial
#pragma unroll
      for (int nh = 0; nh < 4; ++nh)
#pragma unroll
        for (int r = 0; r < 4; ++r) {
          int row = quad * 4 + r;
          int cg = (nh * 2 + (lr >> 3)) ^ (row & 7);
          P[wave][row * 64 + (cg << 3) + (lr & 7)] = (bf16_t)sc[nh][r];
        }
      // per-wave C->A handoff; DS pipe in-order per wave
      __asm__ volatile("s_waitcnt lgkmcnt(0)" ::: "memory");
      bf16x8 pa[2], bv[2][4];
#pragma unroll
      for (int kg = 0; kg < 2; ++kg)
        pa[kg] = *(const bf16x8*)(&P[wave][lr * 64 + (((kg * 4 + quad) ^ (lr & 7)) << 3)]);
#pragma unroll
      for (int kg = 0; kg < 2; ++kg)
#pragma unroll
        for (int nf = 0; nf < 4; ++nf)
          bv[kg][nf] = *(const bf16x8*)(&Vs[cur][(nf * 16 + lr) * 64 + (((kg * 4 + quad) ^ (lr & 7)) << 3)]);
      __asm__ volatile("" ::: "memory");
#pragma unroll
      for (int nf = 0; nf < 4; ++nf) {
        acc[nf] = __builtin_amdgcn_mfma_f32_16x16x32_bf16(pa[0], bv[0][nf], acc[nf], 0, 0, 0);
        acc[nf] = __builtin_amdgcn_mfma_f32_16x16x32_bf16(pa[1], bv[1][nf], acc[nf], 0, 0, 0);
      }
      __syncthreads();                           // prefetched loads drained; buf handoff
      cur ^= 1;
    }

    // one denominator tree per segment (was per-tile)
#pragma unroll
    for (int off = 1; off < 16; off <<= 1)
#pragma unroll
      for (int r = 0; r < 4; ++r) lrow[r] += __shfl_xor(lrow[r], off, 64);

#pragma unroll
    for (int r = 0; r < 4; ++r) {
      float inv = 1.f / lrow[r];
      int row = q0 + quad * 4 + r;
#pragma unroll
      for (int nf = 0; nf < 4; ++nf)
        attn[((size_t)b * SEQ + row) * HIDDEN + h * HD + nf * 16 + lr] =
            (bf16_t)(acc[nf][r] * inv);
    }
  }
}

extern "C" void kernel_launch(void* const* d_in, const int* in_sizes, int n_in,
                              void* d_out, int out_size, void* d_ws, size_t ws_size,
                              hipStream_t stream) {
  float* out = (float*)d_out;

  if (n_in != 4) { k_fill<<<dim3(32768), dim3(256), 0, stream>>>(out, 8388608, 222.0f); return; }
  if (out_size != 8388608) { k_fill<<<dim3(32768), dim3(256), 0, stream>>>(out, 8388608, 111.0f); return; }
  if (ws_size < (size_t)109051904) { k_fill<<<dim3(32768), dim3(256), 0, stream>>>(out, 8388608, 777.0f); return; }

  int ord[4] = {0, 1, 2, 3};
  for (int i = 1; i < 4; ++i)
    for (int j = i; j > 0 && in_sizes[ord[j]] > in_sizes[ord[j - 1]]; --j) {
      int t = ord[j]; ord[j] = ord[j - 1]; ord[j - 1] = t;
    }
  const float*    hidden    = (const float*)d_in[ord[0]];
  const float*    wqkv      = (const float*)d_in[ord[1]];
  const float*    wo        = (const float*)d_in[ord[2]];
  const unsigned* positions = (const unsigned*)d_in[ord[3]];

  char* ws = (char*)d_ws;
  bf16_t* hidB  = (bf16_t*)(ws + 0);
  bf16_t* wqkvT = (bf16_t*)(ws + 16777216);
  bf16_t* woT   = (bf16_t*)(ws + 29360128);
  bf16_t* vbuf  = (bf16_t*)(ws + 37748736);   // 4096 x 512 bf16 = 4 MB
  bf16_t* ql    = (bf16_t*)(ws + 62914560);
  bf16_t* kl    = (bf16_t*)(ws + 79691776);
  bf16_t* vt    = (bf16_t*)(ws + 83886080);
  bf16_t* attnb = (bf16_t*)(ws + 88080384);

  k_cvt<<<dim3(8192), dim3(256), 0, stream>>>(hidden, hidB, 2097152);
  k_tconv<<<dim3(48, 32), dim3(256), 0, stream>>>(wqkv, wqkvT, 2048, 3072);
  k_tconv<<<dim3(32, 32), dim3(256), 0, stream>>>(wo, woT, 2048, 2048);
  k_gemm_qkv<<<dim3(24, 32), dim3(256), 0, stream>>>(hidB, wqkvT, positions, ql, kl, vbuf, 2048);
  k_vtrans<<<dim3(32, 16), dim3(256), 0, stream>>>(vbuf, vt);
  k_attn<<<dim3(16, 64), dim3(256), 0, stream>>>(ql, kl, vt, attnb);
  k_gemm<float><<<dim3(16, 32), dim3(256), 0, stream>>>(attnb, woT, out, 4096, 2048, 2048);
}